// Round 8
// baseline (882.361 us; speedup 1.0000x reference)
//
#include <hip/hip_runtime.h>
#include <hip/hip_bf16.h>
#include <math.h>

// ---------------- constants ----------------
#define B_   8
#define N_   3136
#define C_   768
#define H_   12
#define HD_  64
#define NP_  1046          // pooled seq len: floor((3136+2-3)/3)+1
#define NPP_ 1056          // padded to multiple of 32
#define M_   (B_*N_)       // 25088 rows = 196*128

typedef __bf16 bf16x8 __attribute__((ext_vector_type(8)));
typedef float  f32x4  __attribute__((ext_vector_type(4)));

__device__ __forceinline__ float bf2f(__hip_bfloat16 v){ return __bfloat162float(v); }
__device__ __forceinline__ __hip_bfloat16 f2bf(float v){ return __float2bfloat16(v); }

__device__ __forceinline__ void load_lds16(const void* g, void* l) {
  __builtin_amdgcn_global_load_lds(
      (const __attribute__((address_space(1))) unsigned int*)g,
      (__attribute__((address_space(3))) unsigned int*)l, 16, 0, 0);
}

#define MFMA16(a,b,c) __builtin_amdgcn_mfma_f32_16x16x32_bf16((a),(b),(c),0,0,0)

// ---------------- f32 -> bf16 convert ----------------
__global__ void cvt_kernel(const float* __restrict__ src, __hip_bfloat16* __restrict__ dst, int n) {
  int i = blockIdx.x * 256 + threadIdx.x;
  if (i < n) dst[i] = f2bf(src[i]);
}

// ---------------- LayerNorm (f32 in -> bf16 out), one block per row of 768 ----------------
__global__ __launch_bounds__(256)
void ln_kernel(const float* __restrict__ x, const float* __restrict__ g,
               const float* __restrict__ bta, __hip_bfloat16* __restrict__ out) {
  const size_t row = blockIdx.x;
  const float* xr = x + row * C_;
  const int t = threadIdx.x;
  float v0 = xr[t], v1 = xr[t + 256], v2 = xr[t + 512];
  float s  = v0 + v1 + v2;
  float s2 = v0*v0 + v1*v1 + v2*v2;
  #pragma unroll
  for (int off = 32; off > 0; off >>= 1) { s += __shfl_down(s, off); s2 += __shfl_down(s2, off); }
  __shared__ float ws1[4], ws2[4];
  if ((t & 63) == 0) { ws1[t >> 6] = s; ws2[t >> 6] = s2; }
  __syncthreads();
  float S  = ws1[0] + ws1[1] + ws1[2] + ws1[3];
  float S2 = ws2[0] + ws2[1] + ws2[2] + ws2[3];
  float mean = S * (1.0f / C_);
  float var  = S2 * (1.0f / C_) - mean * mean;
  float rstd = rsqrtf(var + 1e-5f);
  __hip_bfloat16* orow = out + row * C_;
  orow[t]       = f2bf((v0 - mean) * rstd * g[t]       + bta[t]);
  orow[t + 256] = f2bf((v1 - mean) * rstd * g[t + 256] + bta[t + 256]);
  orow[t + 512] = f2bf((v2 - mean) * rstd * g[t + 512] + bta[t + 512]);
}

// ---------------- AvgPool1d(k=3,s=3,p=1,count_include_pad) over seq for K and V ----------------
// kp rows PERMUTED within each 32-block (see round-2 note); vpt natural order.
__global__ void pool_kernel(const __hip_bfloat16* __restrict__ qkv,
                            __hip_bfloat16* __restrict__ kp,
                            __hip_bfloat16* __restrict__ vpt) {
  int idx = blockIdx.x * 256 + threadIdx.x;      // total = 96*NPP_*64
  int d  = idx & 63;
  int np = (idx >> 6) % NPP_;
  int bh = idx / (NPP_ * 64);
  int b = bh / H_, h = bh % H_;
  float ak = 0.f, av = 0.f;
  if (np < NP_) {
    #pragma unroll
    for (int t = 0; t < 3; ++t) {
      int n = np * 3 - 1 + t;
      if (n >= 0 && n < N_) {
        size_t base = ((size_t)b * N_ + n) * (3 * C_) + h * HD_ + d;
        ak += bf2f(qkv[base + C_]);
        av += bf2f(qkv[base + 2 * C_]);
      }
    }
    ak *= (1.0f / 3.0f); av *= (1.0f / 3.0f);
  }
  int c = np & 31;
  int lhi = c >> 3, rr = c & 7;
  int p = (rr < 4) ? (lhi * 4 + rr) : (16 + lhi * 4 + rr - 4);
  kp[((size_t)bh * NPP_ + (np - c) + p) * HD_ + d] = f2bf(ak);
  vpt[((size_t)bh * HD_ + d) * NPP_ + np] = f2bf(av);
}

// ---------------- attention: LDS-staged K/V shared by 4 waves, 128 q-rows/block ----------------
__global__ __launch_bounds__(256)
void attn_kernel(const __hip_bfloat16* __restrict__ qkv,
                 const __hip_bfloat16* __restrict__ kp,
                 const __hip_bfloat16* __restrict__ vpt,
                 __hip_bfloat16* __restrict__ o) {
  __shared__ __align__(16) char smem[16384];   // [2 bufs][K 4KB | V 4KB]
  const int tid  = threadIdx.x;
  const int lane = tid & 63;
  const int w    = tid >> 6;
  const int bh = blockIdx.y;
  const int b = bh / H_, h = bh % H_;
  const int q0 = blockIdx.x * 128 + w * 32;
  const int l15 = lane & 15, lhi = lane >> 4;

  bf16x8 qf[2][2];
  #pragma unroll
  for (int f = 0; f < 2; ++f) {
    int qrow = q0 + f * 16 + l15;
    if (qrow >= N_) qrow = N_ - 1;
    const __hip_bfloat16* qptr = qkv + ((size_t)(b * N_ + qrow)) * (3 * C_) + h * HD_ + lhi * 8;
    qf[f][0] = *(const bf16x8*)(qptr);
    qf[f][1] = *(const bf16x8*)(qptr + 32);
    #pragma unroll
    for (int i = 0; i < 8; ++i) {   // fold in hd^-0.5 = 0.125 (exact)
      qf[f][0][i] = qf[f][0][i] * (__bf16)0.125f;
      qf[f][1][i] = qf[f][1][i] * (__bf16)0.125f;
    }
  }

  const char* kp_base  = (const char*)(kp  + (size_t)bh * NPP_ * HD_);
  const char* vpt_base = (const char*)(vpt + (size_t)bh * HD_ * NPP_);
  const int krow_s = tid >> 3;                 // 0..31
  const int pK = (tid & 7) * 16;
  const int srcKoff = krow_s * 128 + (pK ^ ((krow_s & 7) << 4));
  const int qV = pK ^ ((krow_s & 7) << 4);
  const int vrow_s = 2 * krow_s + (qV >> 6);
  const int srcVoff = vrow_s * (NPP_ * 2) + (qV & 63);

  char* dstK[2] = { smem + 0    + w * 1024, smem + 8192 + 0    + w * 1024 };
  char* dstV[2] = { smem + 4096 + w * 1024, smem + 8192 + 4096 + w * 1024 };

  load_lds16(kp_base + srcKoff, dstK[0]);
  load_lds16(vpt_base + srcVoff, dstV[0]);
  __syncthreads();

  f32x4 oacc[2][4] = {};
  float lp[2] = {0.f, 0.f};

  for (int kc = 0; kc < NPP_; kc += 32) {
    const int cur = (kc >> 5) & 1;
    if (kc + 32 < NPP_) {
      load_lds16(kp_base + (size_t)(kc + 32) * 128 + srcKoff, dstK[cur ^ 1]);
      load_lds16(vpt_base + (size_t)(kc + 32) * 2 + srcVoff, dstV[cur ^ 1]);
    }
    const char* sK = smem + cur * 8192;
    const char* sV = smem + cur * 8192 + 4096;

    bf16x8 ka0 = *(const bf16x8*)(sK + l15 * 128        + (( 0 + 16 * lhi) ^ ((l15 & 7) << 4)));
    bf16x8 ka1 = *(const bf16x8*)(sK + l15 * 128        + ((64 + 16 * lhi) ^ ((l15 & 7) << 4)));
    bf16x8 kb0 = *(const bf16x8*)(sK + (16 + l15) * 128 + (( 0 + 16 * lhi) ^ ((l15 & 7) << 4)));
    bf16x8 kb1 = *(const bf16x8*)(sK + (16 + l15) * 128 + ((64 + 16 * lhi) ^ ((l15 & 7) << 4)));
    bf16x8 vf[4];
    #pragma unroll
    for (int nb = 0; nb < 4; ++nb) {
      int row = nb * 16 + l15;
      int Lv = row >> 1;
      int p = (((row & 1) * 64) + 16 * lhi) ^ ((Lv & 7) << 4);
      vf[nb] = *(const bf16x8*)(sV + Lv * 128 + p);
    }

    #pragma unroll
    for (int f = 0; f < 2; ++f) {
      f32x4 s0 = {}, s1 = {};
      s0 = MFMA16(ka0, qf[f][0], s0);
      s0 = MFMA16(ka1, qf[f][1], s0);
      s1 = MFMA16(kb0, qf[f][0], s1);
      s1 = MFMA16(kb1, qf[f][1], s1);
      bf16x8 pa;
      #pragma unroll
      for (int r = 0; r < 4; ++r) {
        float p0 = (kc + lhi * 8 + r     < NP_) ? __expf(s0[r]) : 0.f;
        float p1 = (kc + lhi * 8 + 4 + r < NP_) ? __expf(s1[r]) : 0.f;
        lp[f] += p0 + p1;
        pa[r]     = (__bf16)p0;
        pa[r + 4] = (__bf16)p1;
      }
      #pragma unroll
      for (int nb = 0; nb < 4; ++nb)
        oacc[f][nb] = MFMA16(pa, vf[nb], oacc[f][nb]);
    }
    __syncthreads();
  }

  #pragma unroll
  for (int f = 0; f < 2; ++f) {
    float lpf = lp[f];
    lpf += __shfl_xor(lpf, 16);
    lpf += __shfl_xor(lpf, 32);
    #pragma unroll
    for (int r = 0; r < 4; ++r) {
      int orow = q0 + f * 16 + lhi * 4 + r;
      if (orow < N_) {
        float inv = 1.0f / __shfl(lpf, lhi * 4 + r);
        size_t rowbase = ((size_t)(b * N_ + orow)) * C_ + h * HD_;
        #pragma unroll
        for (int nb = 0; nb < 4; ++nb)
          o[rowbase + nb * 16 + l15] = f2bf(oacc[f][nb][r] * inv);
      }
    }
  }
}

// ---------------- 128x128 deep-pipelined GEMM (BK=32, 4 LDS bufs, counted vmcnt) ----------------
// C(M,N) = A(M,K)*Bt(N,K)^T. 256 thr / 4 waves (2x2), per-wave 64x64. LDS 64 KB ->
// 2 blocks/CU (launch_bounds(256,2)); the two resident blocks' barrier groups de-phase
// and hide each other's latency (this beat the 256^2 1-block/CU 8-phase structure by
// ~1.5x in-bench, r6->r7). Pipeline: stage t0,t1,t2; per phase t: {ds_read frags(t);
// stage t+3; vmcnt(8); barrier; 16 MFMA (setprio)}. Tail: vmcnt(4)/vmcnt(0).
// EPI 0: out bf16 = acc ; 1: out f32 = acc + bias[col] + res[idx] ;
// EPI 2: out bf16 = gelu(acc + bias[col]) (exact erf gelu)
template<int EPI>
__global__ __launch_bounds__(256, 2)
void gemm128(const __hip_bfloat16* __restrict__ A,
             const __hip_bfloat16* __restrict__ Bt,
             const float* __restrict__ bias,
             const float* __restrict__ res, void* outv,
             int M, int N, int K) {
  __shared__ __align__(16) __hip_bfloat16 sA[4][128 * 32];
  __shared__ __align__(16) __hip_bfloat16 sB[4][128 * 32];
  const int tid = threadIdx.x, lane = tid & 63, wid = tid >> 6;
  const int wr = wid >> 1, wc = wid & 1;
  const int l15 = lane & 15, lhi = lane >> 4;

  // bijective XCD swizzle, col-fast
  const int nwg = gridDim.x;
  const int ntx = N >> 7;
  const int qq = nwg >> 3, rr8 = nwg & 7;
  const int xcd = blockIdx.x & 7, off8 = blockIdx.x >> 3;
  const int wg = (xcd < rr8 ? xcd * (qq + 1) : rr8 * (qq + 1) + (xcd - rr8) * qq) + off8;
  const long row0 = (long)(wg / ntx) * 128;
  const long col0 = (long)(wg % ntx) * 128;

  const size_t ldb = (size_t)K * 2;
  // staging: source pre-swizzled (col16 ^ ((row&3)<<4)); LDS dest linear (lane*16)
  const int R = tid >> 2;                                // rows 0..63 (+64 on 2nd load)
  const int scol = ((tid & 3) * 16) ^ ((R & 3) << 4);
  const char* gA = (const char*)A  + (size_t)(row0 + R) * ldb + scol;
  const char* gB = (const char*)Bt + (size_t)(col0 + R) * ldb + scol;

  const int fsw = (lhi * 16) ^ ((l15 & 3) << 4);         // read-side swizzle

  f32x4 acc[4][4] = {};

#define STG(b, t) { \
    const char* ga_ = gA + (size_t)(t) * 64; \
    const char* gb_ = gB + (size_t)(t) * 64; \
    char* la_ = (char*)&sA[b][0] + wid * 1024; \
    char* lb_ = (char*)&sB[b][0] + wid * 1024; \
    load_lds16(ga_, la_); \
    load_lds16(ga_ + 64 * ldb, la_ + 4096); \
    load_lds16(gb_, lb_); \
    load_lds16(gb_ + 64 * ldb, lb_ + 4096); }

  const int NT = K >> 5;
  STG(0, 0); STG(1, 1); STG(2, 2);
  asm volatile("s_waitcnt vmcnt(8)" ::: "memory");   // t0 landed; t1,t2 in flight
  __syncthreads();

  for (int t = 0; t < NT; ++t) {
    const int b = t & 3;
    bf16x8 af[4], bfv[4];
    const char* pa_ = (const char*)&sA[b][0] + (wr * 64 + l15) * 64 + fsw;
    const char* pb_ = (const char*)&sB[b][0] + (wc * 64 + l15) * 64 + fsw;
    #pragma unroll
    for (int m = 0; m < 4; ++m) af[m]  = *(const bf16x8*)(pa_ + m * 16 * 64);
    #pragma unroll
    for (int n = 0; n < 4; ++n) bfv[n] = *(const bf16x8*)(pb_ + n * 16 * 64);
    if (t + 3 < NT) {
      STG((t + 3) & 3, t + 3);
      asm volatile("s_waitcnt vmcnt(8)" ::: "memory");
    } else if (t + 2 < NT) {
      asm volatile("s_waitcnt vmcnt(4)" ::: "memory");
    } else if (t + 1 < NT) {
      asm volatile("s_waitcnt vmcnt(0)" ::: "memory");
    }
    __builtin_amdgcn_sched_barrier(0);
    __builtin_amdgcn_s_barrier();
    __builtin_amdgcn_sched_barrier(0);
    __builtin_amdgcn_s_setprio(1);
    #pragma unroll
    for (int m = 0; m < 4; ++m)
      #pragma unroll
      for (int n = 0; n < 4; ++n)
        acc[m][n] = MFMA16(af[m], bfv[n], acc[m][n]);
    __builtin_amdgcn_s_setprio(0);
  }
#undef STG

  #pragma unroll
  for (int m = 0; m < 4; ++m) {
    long rbase = row0 + wr * 64 + m * 16 + lhi * 4;
    #pragma unroll
    for (int n = 0; n < 4; ++n) {
      long col = col0 + wc * 64 + n * 16 + l15;
      #pragma unroll
      for (int r = 0; r < 4; ++r) {
        size_t idx = (size_t)(rbase + r) * N + col;
        float v = acc[m][n][r];
        if (EPI == 0) {
          ((__hip_bfloat16*)outv)[idx] = f2bf(v);
        } else if (EPI == 1) {
          ((float*)outv)[idx] = v + bias[col] + res[idx];
        } else {
          v += bias[col];
          float gl = 0.5f * v * (1.0f + erff(v * 0.70710678118f));
          ((__hip_bfloat16*)outv)[idx] = f2bf(gl);
        }
      }
    }
  }
}

// ---------------- launch ----------------
extern "C" void kernel_launch(void* const* d_in, const int* in_sizes, int n_in,
                              void* d_out, int out_size, void* d_ws, size_t ws_size,
                              hipStream_t stream) {
  const float* x      = (const float*)d_in[0];
  const float* ln1_g  = (const float*)d_in[1];
  const float* ln1_b  = (const float*)d_in[2];
  const float* qkv_w  = (const float*)d_in[3];
  const float* proj_w = (const float*)d_in[4];
  const float* proj_b = (const float*)d_in[5];
  const float* ln2_g  = (const float*)d_in[6];
  const float* ln2_b  = (const float*)d_in[7];
  const float* fc1_w  = (const float*)d_in[8];
  const float* fc1_b  = (const float*)d_in[9];
  const float* fc2_w  = (const float*)d_in[10];
  const float* fc2_b  = (const float*)d_in[11];
  float* out = (float*)d_out;

  // workspace layout (bytes)
  char* ws = (char*)d_ws;
  __hip_bfloat16* wqkv  = (__hip_bfloat16*)(ws + 0);          // 2304*768*2  = 3538944
  __hip_bfloat16* wproj = (__hip_bfloat16*)(ws + 3538944);    // 768*768*2   = 1179648
  __hip_bfloat16* wfc1  = (__hip_bfloat16*)(ws + 4718592);    // 3072*768*2  = 4718592
  __hip_bfloat16* wfc2  = (__hip_bfloat16*)(ws + 9437184);    // 768*3072*2  = 4718592
  __hip_bfloat16* hbuf  = (__hip_bfloat16*)(ws + 14155776);   // 25088*768*2 = 38535168 (LN1 out, later LN2 out)
  __hip_bfloat16* obuf  = (__hip_bfloat16*)(ws + 52690944);   // 25088*768*2 = 38535168 (attn out)
  __hip_bfloat16* kpb   = (__hip_bfloat16*)(ws + 91226112);   // 96*1056*64*2 = 12976128
  __hip_bfloat16* vptb  = (__hip_bfloat16*)(ws + 104202240);  // 12976128
  __hip_bfloat16* big   = (__hip_bfloat16*)(ws + 117178368);  // max(qkv 115605504, m1 154140672)
  const size_t WS_NEEDED = 117178368ull + 154140672ull;       // ~271.3 MB
  if (ws_size < WS_NEEDED) return;  // insufficient workspace; fail cleanly

  // weights -> bf16
  cvt_kernel<<<(2304 * 768 + 255) / 256, 256, 0, stream>>>(qkv_w,  wqkv, 2304 * 768);
  cvt_kernel<<<(768 * 768 + 255) / 256, 256, 0, stream>>>(proj_w, wproj, 768 * 768);
  cvt_kernel<<<(3072 * 768 + 255) / 256, 256, 0, stream>>>(fc1_w,  wfc1, 3072 * 768);
  cvt_kernel<<<(768 * 3072 + 255) / 256, 256, 0, stream>>>(fc2_w,  wfc2, 768 * 3072);

  // attention sublayer
  ln_kernel<<<M_, 256, 0, stream>>>(x, ln1_g, ln1_b, hbuf);
  gemm128<0><<<(M_ / 128) * (2304 / 128), 256, 0, stream>>>(hbuf, wqkv, nullptr, nullptr, big, M_, 2304, 768);
  pool_kernel<<<(96 * NPP_ * 64) / 256, 256, 0, stream>>>(big, kpb, vptb);
  attn_kernel<<<dim3((N_ + 127) / 128, B_ * H_), 256, 0, stream>>>(big, kpb, vptb, obuf);
  gemm128<1><<<(M_ / 128) * (768 / 128), 256, 0, stream>>>(obuf, wproj, proj_b, x, out, M_, 768, 768);

  // MLP sublayer (x1 lives in d_out)
  ln_kernel<<<M_, 256, 0, stream>>>(out, ln2_g, ln2_b, hbuf);
  gemm128<2><<<(M_ / 128) * (3072 / 128), 256, 0, stream>>>(hbuf, wfc1, fc1_b, nullptr, big, M_, 3072, 768);
  gemm128<1><<<(M_ / 128) * (768 / 128), 256, 0, stream>>>(big, wfc2, fc2_b, out, out, M_, 768, 3072);
}